// Round 4
// baseline (208.877 us; speedup 1.0000x reference)
//
#include <hip/hip_runtime.h>
#include <stdint.h>

#define EPSV 1e-5f

typedef int v4i __attribute__((ext_vector_type(4)));

__device__ __forceinline__ v4i mfma16(v4i a, v4i b, v4i c) {
    return __builtin_amdgcn_mfma_i32_16x16x64_i8(a, b, c, 0, 0, 0);
}

// epilogue first stage: BN + ReLU-u4 quant -> r index in [0,15].
__device__ __forceinline__ int q_r(int s, float fscale, float inv, float beta,
                                   float s_relu)
{
#pragma clang fp contract(off)
    float y = (float)s * fscale;
    y = y * inv;
    y = y + beta;
    float r = rintf(y / s_relu);
    r = fminf(fmaxf(r, 0.f), 15.f);
    return (int)r;
}

// ---------------------------------------------------------------------------
// Pack kernel (computes per-layer weight scale in-block).
//  seg B    : conv weights -> MFMA B-fragment order (52992 dwords)
//  seg HEAD : head weights -> MFMA B-fragment order, NT=3 (768 dwords)
//  seg BN   : inv/beta (8*128 floats) + requant LUTs (144 int8)
// ---------------------------------------------------------------------------
struct PackArgs {
    const float* w[9];
    const float* bn[8];
    const float* sc;
    float* smaxf;
    int* qw;
    float* bnp;
    int8_t* lut;
};

#define NB_B    207
#define NB_HEAD 3
#define NB_BN   3

__global__ __launch_bounds__(256) void k_pack(PackArgs a)
{
#pragma clang fp contract(off)
    __shared__ float red[4];
    const int blk = blockIdx.x;
    if (blk < NB_B + NB_HEAD) {
        const int bcum[10] = {0, 256, 1792, 6912, 16128, 25344, 34560, 43776,
                              52992, 53760};
        const int wnn[9] = {432, 4608, 18432, 36864, 36864, 36864, 36864, 36864, 2304};
        const int u = blk * 256 + threadIdx.x;
        int L = 0;
        while (u >= bcum[L + 1]) ++L;          // uniform per block
        const float* w = a.w[L];
        const int n = wnn[L];

        // in-block layer max|w| (exact; order-independent)
        float mm = 0.f;
        for (int i = threadIdx.x; i < n; i += 256) mm = fmaxf(mm, fabsf(w[i]));
#pragma unroll
        for (int off = 32; off > 0; off >>= 1) mm = fmaxf(mm, __shfl_down(mm, off));
        if ((threadIdx.x & 63) == 0) red[threadIdx.x >> 6] = mm;
        __syncthreads();
        const float wmax = fmaxf(fmaxf(red[0], red[1]), fmaxf(red[2], red[3]));
        const float s = wmax / 7.0f;
        if (blk * 256 == bcum[L] && threadIdx.x == 0) a.smaxf[L] = wmax;

        if (L < 8) {
            const int CIGA[8] = {1, 4, 8, 16, 16, 16, 16, 16};
            const int COA[8]  = {16, 32, 64, 64, 64, 64, 64, 64};
            const int NTA[8]  = {1, 2, 4, 4, 4, 4, 4, 4};
            const int CINA[8] = {3, 16, 32, 64, 64, 64, 64, 64};
            const int rem = u - bcum[L];
            const int d = rem & 3;
            const int lane = (rem >> 2) & 63;
            const int gnt = rem >> 8;
            const int NT = NTA[L];
            const int nt = gnt % NT;
            const int g = gnt / NT;
            const int CIG = CIGA[L], CIN = CINA[L], CO = COA[L];
            const int TG = 16 / CIG;
            const int nn = nt * 16 + (lane & 15);
            unsigned dw = 0;
            for (int jb = 0; jb < 4; ++jb) {
                const int k = 16 * (lane >> 4) + 4 * d + jb;
                const int tap = g * TG + k / (4 * CIG);
                const int ci = k % (4 * CIG);
                int qv = 0;
                if (tap < 9 && ci < CIN && nn < CO) {
                    float rr = rintf(w[(nn * CIN + ci) * 9 + tap] / s);
                    rr = fminf(fmaxf(rr, -7.f), 7.f);
                    qv = (int)rr;
                }
                dw |= ((unsigned)(qv & 0xff)) << (8 * jb);
            }
            a.qw[u] = (int)dw;
        } else {
            const int uh = u - 52992;           // 0..767
            const int d = uh & 3;
            const int lane = (uh >> 2) & 63;
            const int nt = uh >> 8;             // 0..2
            const int nn = nt * 16 + (lane & 15);
            unsigned dw = 0;
            for (int jb = 0; jb < 4; ++jb) {
                const int ci = 16 * (lane >> 4) + 4 * d + jb;   // K=64 = cin
                int qv = 0;
                if (nn < 36) {
                    float rr = rintf(w[nn * 64 + ci] / s);
                    rr = fminf(fmaxf(rr, -7.f), 7.f);
                    qv = (int)rr;
                }
                dw |= ((unsigned)(qv & 0xff)) << (8 * jb);
            }
            a.qw[u] = (int)dw;
        }
    } else {
        const int id = (blk - NB_B - NB_HEAD) * 256 + threadIdx.x;
        if (id < 512) {
            const int l = id >> 6, c = id & 63;
            const int C[8] = {16, 32, 64, 64, 64, 64, 64, 64};
            if (c < C[l]) {
                const float* bn = a.bn[l];
                const int Cl = C[l];
                float g = bn[c], b = bn[Cl + c], m = bn[2 * Cl + c], v = bn[3 * Cl + c];
                float inv = g / sqrtf(v + EPSV);
                float mi = m * inv;
                a.bnp[l * 128 + c] = inv;
                a.bnp[l * 128 + 64 + c] = b - mi;
            }
        } else if (id < 656) {
            // requant LUTs. l=0..7: relu-u4 r -> next-layer signed code
            //               l=8   : conv0 input double-quant, idx = r0+8
            const int j = id - 512;
            const int l = j >> 4, r = j & 15;
            float code;
            if (l < 8) {
                const float s_relu = a.sc[10 + l];
                const float s_next = (l < 7) ? a.sc[2 + l] : a.sc[9];
                const float v = (float)r * s_relu;          // bit-exact: r*s_relu
                code = fminf(fmaxf(rintf(v / s_next), -8.f), 7.f);
            } else {
                const float v = (float)(r - 8) * a.sc[0];
                code = fminf(fmaxf(rintf(v / a.sc[1]), -8.f), 7.f);
            }
            a.lut[j] = (int8_t)(int)code;
        }
    }
}

// ---------------------------------------------------------------------------
// L0 fused: fake-quant of fp32 x (NCHW) during tile staging (1 div + LUT) +
// MFMA conv 3->16ch + BN/ReLU-quant(LUT)/pool. out NHWC [16][160][320][16].
// grid (10, 40, 16); tile 10x66 px, CIG=1.
// ---------------------------------------------------------------------------
__global__ __launch_bounds__(256) void k_conv0(
    const float* __restrict__ x, int8_t* __restrict__ out,
    const int* __restrict__ bfrag, const float* __restrict__ scales,
    const float* __restrict__ smaxf, const float* __restrict__ bnp,
    const int8_t* __restrict__ luts)
{
#pragma clang fp contract(off)
    __shared__ int tile[660];        // 10 * 66
    __shared__ float bnl[128];
    __shared__ int8_t lc[32];        // [0..15] layer0 epi lut, [16..31] input lut

    const int b = blockIdx.z;
    const int py0 = blockIdx.y * 4;
    const int px0 = blockIdx.x * 32;
    const int ty0 = 2 * py0 - 1;
    const int tx0 = 2 * px0 - 1;
    const float s0 = scales[0];

    if (threadIdx.x < 16) lc[threadIdx.x] = luts[threadIdx.x];
    else if (threadIdx.x < 32) lc[threadIdx.x] = luts[128 + threadIdx.x - 16];
    if (threadIdx.x < 128) bnl[threadIdx.x] = bnp[threadIdx.x];
    __syncthreads();

    for (int i = threadIdx.x; i < 660; i += 256) {
        const int ly = i / 66;
        const int lx = i - ly * 66;
        const int gy = ty0 + ly, gx = tx0 + lx;
        int v = 0;
        if ((unsigned)gy < 320u && (unsigned)gx < 640u) {
#pragma unroll
            for (int ci = 0; ci < 3; ++ci) {
                float xv = x[((size_t)(b * 3 + ci) * 320 + gy) * 640 + gx];
                float r = rintf(xv / s0);
                r = fminf(fmaxf(r, -8.f), 7.f);
                v |= ((int)lc[16 + (int)r + 8] & 0xff) << (8 * ci);
            }
        }
        tile[i] = v;
    }

    const int lane = threadIdx.x & 63;
    const int wv = threadIdx.x >> 6;
    const v4i bfv = *(const v4i*)&bfrag[lane * 4];
    __syncthreads();

    const int q = lane >> 4;
    const int m = lane & 15;
    const int px_sub = m >> 2;
    const int op = m & 3;
    const int lyb = 2 * wv + (op >> 1);
    const int lxb0 = 2 * px_sub + (op & 1);

    const float sw = smaxf[0] / 7.0f;
    const float fscale = scales[1] * sw;
    const float s_relu = scales[10];
    const float inv = bnl[m];
    const float beta = bnl[64 + m];
    const int py = py0 + wv;

    for (int xs = 0; xs < 8; ++xs) {
        v4i af;
#pragma unroll
        for (int d = 0; d < 4; ++d) {
            int t = 4 * q + d; t = min(t, 8);
            const int ky = (t * 11) >> 5;
            const int kx = t - 3 * ky;
            af[d] = tile[(lyb + ky) * 66 + 8 * xs + lxb0 + kx];
        }
        v4i acc = mfma16(af, bfv, (v4i){0, 0, 0, 0});
        const int px = px0 + 4 * xs + q;
        const int s = max(max(acc[0], acc[1]), max(acc[2], acc[3]));
        const int ri = q_r(s, fscale, inv, beta, s_relu);
        out[((size_t)((b * 160 + py) * 320 + px)) * 16 + m] = lc[ri];
    }
}

// ---------------------------------------------------------------------------
// MFMA pool-conv block (L1..L3). NHWC int8 in/out. B fragments: registers
// when small (L1), else direct per-MFMA global reads (L2-hot; tail-proven).
// A fragments: preloaded NG-deep register array per strip (break the
// ds_read->mfma serial chain; pipelined independent b128 reads).
// ---------------------------------------------------------------------------
template <int CIG, int CO, int H, int W, int XL>
__global__ __launch_bounds__(256) void k_mpool(
    const int8_t* __restrict__ in, int8_t* __restrict__ out,
    const int* __restrict__ bfrag, const float* __restrict__ scales,
    const float* __restrict__ smaxf, const float* __restrict__ bnp,
    const int8_t* __restrict__ luts, int layer, int sin_idx, int srelu_idx)
{
#pragma clang fp contract(off)
    constexpr int NT = CO / 16;
    constexpr int TG = 16 / CIG;              // taps per K=64 group
    constexpr int NG = (9 + TG - 1) / TG;     // K groups
    constexpr int TLH = 2 * 4 + 2;            // NROWS=4, stride 2
    constexpr int TLW = 2 * 4 * XL + 2;
    constexpr int TILE_DW = TLH * TLW * CIG;
    constexpr bool PRELOAD = (NG * NT <= 8);
    constexpr int Ho = H / 2, Wo = W / 2;

    __shared__ int tile[TILE_DW];
    __shared__ float bnl[128];
    __shared__ int8_t lsh[16];

    const int b = blockIdx.z;
    const int py0 = blockIdx.y * 4;
    const int px0 = blockIdx.x * (4 * XL);
    const int ty0 = 2 * py0 - 1;
    const int tx0 = 2 * px0 - 1;
    const int* gin = (const int*)in;

    // b128 staging: each 4-dword chunk lies within one pixel (CIG >= 4)
    for (int i = threadIdx.x; i < TILE_DW / 4; i += 256) {
        const int j = 4 * i;
        const int cig = j & (CIG - 1);
        const int rest = j / CIG;
        const int lx = rest % TLW;
        const int ly = rest / TLW;
        const int gy = ty0 + ly, gx = tx0 + lx;
        v4i v = {0, 0, 0, 0};
        if ((unsigned)gy < (unsigned)H && (unsigned)gx < (unsigned)W)
            v = *(const v4i*)&gin[((b * H + gy) * W + gx) * CIG + cig];
        *(v4i*)&tile[j] = v;
    }
    if (threadIdx.x < 128) bnl[threadIdx.x] = bnp[layer * 128 + threadIdx.x];
    if (threadIdx.x >= 128 && threadIdx.x < 144)
        lsh[threadIdx.x - 128] = luts[layer * 16 + threadIdx.x - 128];

    const int lane = threadIdx.x & 63;
    const int wv = threadIdx.x >> 6;
    v4i breg[PRELOAD ? NG * NT : 1];
    if constexpr (PRELOAD) {
#pragma unroll
        for (int i = 0; i < NG * NT; ++i)
            breg[i] = *(const v4i*)&bfrag[(i * 64 + lane) * 4];
    }
    __syncthreads();

    const int q = lane >> 4;
    const int m = lane & 15;

    const float fscale = scales[sin_idx] * (smaxf[layer] / 7.0f);
    const float s_relu = scales[srelu_idx];

    const int px_sub = m >> 2;
    const int op = m & 3;
    const int lyb = 2 * wv + (op >> 1);
    const int lxb0 = 2 * px_sub + (op & 1);
    const int py = py0 + wv;

    for (int xs = 0; xs < XL; ++xs) {
        // --- preload all NG A-fragments (independent, pipelined) ---
        v4i afv[NG];
#pragma unroll
        for (int g = 0; g < NG; ++g) {
            if constexpr (CIG == 16) {
                const int ky = (g * 11) >> 5;
                const int kx = g - 3 * ky;
                const int addr = ((lyb + ky) * TLW + (8 * xs + lxb0 + kx)) * 16 + 4 * q;
                afv[g] = *(const v4i*)&tile[addr];
            } else if constexpr (CIG == 8) {
                int t = 2 * g + (q >> 1); t = min(t, 8);
                const int ky = (t * 11) >> 5;
                const int kx = t - 3 * ky;
                const int addr = ((lyb + ky) * TLW + (8 * xs + lxb0 + kx)) * 8 + 4 * (q & 1);
                afv[g] = *(const v4i*)&tile[addr];
            } else {  // CIG == 4
                int t = 4 * g + q; t = min(t, 8);
                const int ky = (t * 11) >> 5;
                const int kx = t - 3 * ky;
                const int addr = ((lyb + ky) * TLW + (8 * xs + lxb0 + kx)) * 4;
                afv[g] = *(const v4i*)&tile[addr];
            }
        }

        v4i acc[NT];
#pragma unroll
        for (int j = 0; j < NT; ++j) acc[j] = (v4i){0, 0, 0, 0};

#pragma unroll
        for (int g = 0; g < NG; ++g) {
#pragma unroll
            for (int j = 0; j < NT; ++j) {
                v4i bf;
                if constexpr (PRELOAD) bf = breg[g * NT + j];
                else bf = *(const v4i*)&bfrag[((g * NT + j) * 64 + lane) * 4];
                acc[j] = mfma16(afv[g], bf, acc[j]);
            }
        }

        const int px = px0 + 4 * xs + q;
        int8_t* po = out + ((size_t)((b * Ho + py) * Wo + px)) * CO + m;
#pragma unroll
        for (int j = 0; j < NT; ++j) {
            const int co = j * 16 + m;
            const int s = max(max(acc[j][0], acc[j][1]), max(acc[j][2], acc[j][3]));
            const int ri = q_r(s, fscale, bnl[co], bnl[64 + co], s_relu);
            po[j * 16] = lsh[ri];
        }
    }
}

// ---------------------------------------------------------------------------
// Tail conv (L4..L7): 20x40x64, 3x3 SAME, nonpool. grid (3,10,16), 4 waves,
// 2 rows x 16 px per block. B fragments preloaded to regs BEFORE the barrier
// (hides B latency under LDS staging); A fragments preloaded 9-deep; MFMA
// burst is pure-register. FUSED: append 1x1 head (64->36)+bias -> fp32 NCHW.
// ---------------------------------------------------------------------------
template <bool FUSED>
__global__ __launch_bounds__(256) void k_mtail(
    const int8_t* __restrict__ in, int8_t* __restrict__ out,
    const int* __restrict__ bfrag, const float* __restrict__ scales,
    const float* __restrict__ smaxf, const float* __restrict__ bnp,
    const int8_t* __restrict__ luts, int layer, int sin_idx, int srelu_idx,
    const int* __restrict__ hfrag, const float* __restrict__ b9,
    float* __restrict__ dout)
{
#pragma clang fp contract(off)
    constexpr int TLW = 18;
    constexpr int TILE_DW = 4 * TLW * 16;
    __shared__ int tile[TILE_DW];
    __shared__ float bnl[128];
    __shared__ int8_t lsh[16];
    __shared__ int code_dw[FUSED ? 512 : 1];

    const int b = blockIdx.z;
    const int py0 = blockIdx.y * 2;
    const int px0 = blockIdx.x * 16;
    const int ty0 = py0 - 1;
    const int tx0 = px0 - 1;
    const int* gin = (const int*)in;

    for (int i = threadIdx.x; i < TILE_DW / 4; i += 256) {
        const int j = 4 * i;
        const int cig = j & 15;
        const int rest = j >> 4;
        const int lx = rest % TLW;
        const int ly = rest / TLW;
        const int gy = ty0 + ly, gx = tx0 + lx;
        v4i v = {0, 0, 0, 0};
        if ((unsigned)gy < 20u && (unsigned)gx < 40u)
            v = *(const v4i*)&gin[((b * 20 + gy) * 40 + gx) * 16 + cig];
        *(v4i*)&tile[j] = v;
    }
    if (threadIdx.x < 128) bnl[threadIdx.x] = bnp[layer * 128 + threadIdx.x];
    if (threadIdx.x >= 128 && threadIdx.x < 144)
        lsh[threadIdx.x - 128] = luts[layer * 16 + threadIdx.x - 128];

    const int lane = threadIdx.x & 63;
    const int wv = threadIdx.x >> 6;
    const int q = lane >> 4;
    const int m = lane & 15;
    const int wrow = wv >> 1;
    const int nt0 = (wv & 1) * 2;

    // B preload BEFORE barrier: latency overlaps the staging drain
    v4i bl[18];
#pragma unroll
    for (int g = 0; g < 9; ++g)
#pragma unroll
        for (int jj = 0; jj < 2; ++jj)
            bl[g * 2 + jj] = *(const v4i*)&bfrag[((g * 4 + nt0 + jj) * 64 + lane) * 4];
    __syncthreads();

    const float fscale = scales[sin_idx] * (smaxf[layer] / 7.0f);
    const float s_relu = scales[srelu_idx];

    // A preload: 9 independent b128 reads, then pure-register MFMA burst
    v4i afv[9];
#pragma unroll
    for (int g = 0; g < 9; ++g) {
        const int ky = (g * 11) >> 5;
        const int kx = g - 3 * ky;
        afv[g] = *(const v4i*)&tile[((wrow + ky) * TLW + (m + kx)) * 16 + 4 * q];
    }

    v4i acc[2];
    acc[0] = (v4i){0, 0, 0, 0};
    acc[1] = (v4i){0, 0, 0, 0};
#pragma unroll
    for (int g = 0; g < 9; ++g)
#pragma unroll
        for (int jj = 0; jj < 2; ++jj)
            acc[jj] = mfma16(afv[g], bl[g * 2 + jj], acc[jj]);

    const int py = py0 + wrow;
#pragma unroll
    for (int jj = 0; jj < 2; ++jj) {
        const int co = (nt0 + jj) * 16 + m;
        const float inv = bnl[co], beta = bnl[64 + co];
#pragma unroll
        for (int r = 0; r < 4; ++r) {
            const int px = px0 + 4 * q + r;
            const int ri = q_r(acc[jj][r], fscale, inv, beta, s_relu);
            if constexpr (FUSED) {
                ((int8_t*)code_dw)[(wrow * 16 + 4 * q + r) * 64 + co] = lsh[ri];
            } else {
                if (px < 40)
                    out[((size_t)((b * 20 + py) * 40 + px)) * 64 + co] = lsh[ri];
            }
        }
    }

    if constexpr (FUSED) {
        __syncthreads();
        if (wv < 2) {
            const v4i ha = *(const v4i*)&code_dw[(wv * 16 + m) * 16 + 4 * q];
            const float fs = scales[9] * (smaxf[8] / 7.0f);
            const int py2 = py0 + wv;
#pragma unroll
            for (int nt = 0; nt < 3; ++nt) {
                const v4i hb = *(const v4i*)&hfrag[(nt * 64 + lane) * 4];
                const v4i hacc = mfma16(ha, hb, (v4i){0, 0, 0, 0});
                const int co = nt * 16 + m;
                if (co < 36) {
                    const float bias = b9[co];
#pragma unroll
                    for (int r = 0; r < 4; ++r) {
                        const int px = px0 + 4 * q + r;
                        if (px < 40) {
                            float yv = (float)hacc[r] * fs;
                            dout[((size_t)(b * 36 + co)) * 800 + py2 * 40 + px] = yv + bias;
                        }
                    }
                }
            }
        }
    }
}

// ---------------------------------------------------------------------------
// Launch: 9 regular dispatches
// ---------------------------------------------------------------------------
extern "C" void kernel_launch(void* const* d_in, const int* in_sizes, int n_in,
                              void* d_out, int out_size, void* d_ws, size_t ws_size,
                              hipStream_t stream)
{
    const float* x = (const float*)d_in[0];
    const float* w[9];
    for (int i = 0; i < 9; i++) w[i] = (const float*)d_in[1 + i];
    const float* b9 = (const float*)d_in[10];
    const float* bn[8];
    for (int i = 0; i < 8; i++) bn[i] = (const float*)d_in[11 + i];
    const float* scales = (const float*)d_in[19];

    int8_t* base = (int8_t*)d_ws;
    int8_t* bufA = base;                             // 13,107,200 B
    int8_t* bufB = base + 13107200;                  // 13,107,200 B
    int*     qw  = (int*)(base + 26214400);          // 53760 dwords
    float* smaxf = (float*)(base + 26429440);        // 9 floats
    float*   bnp = (float*)(base + 26429504);        // 1024 floats
    int8_t* luts = base + 26433600;                  // 144 B

    PackArgs pa;
    for (int i = 0; i < 9; i++) pa.w[i] = w[i];
    for (int i = 0; i < 8; i++) pa.bn[i] = bn[i];
    pa.sc = scales; pa.smaxf = smaxf;
    pa.qw = qw; pa.bnp = bnp; pa.lut = luts;
    k_pack<<<NB_B + NB_HEAD + NB_BN, 256, 0, stream>>>(pa);

    // L0: fp32 x -> NHWC codes [16][160][320][16] in bufB
    k_conv0<<<dim3(10, 40, 16), 256, 0, stream>>>(
        x, bufB, qw, scales, smaxf, bnp, luts);

    // L1: CIG=4, CO=32, 160x320 -> 80x160, XL=8 (32 px/block)
    k_mpool<4, 32, 160, 320, 8><<<dim3(5, 20, 16), 256, 0, stream>>>(
        bufB, bufA, qw + 256, scales, smaxf, bnp, luts, 1, 2, 11);
    // L2: CIG=8, CO=64, 80x160 -> 40x80 (direct global B)
    k_mpool<8, 64, 80, 160, 2><<<dim3(10, 10, 16), 256, 0, stream>>>(
        bufA, bufB, qw + 1792, scales, smaxf, bnp, luts, 2, 3, 12);
    // L3: CIG=16, CO=64, 40x80 -> 20x40 (direct global B)
    k_mpool<16, 64, 40, 80, 1><<<dim3(10, 5, 16), 256, 0, stream>>>(
        bufB, bufA, qw + 6912, scales, smaxf, bnp, luts, 3, 4, 13);

    // L4..L7 (+ fused head on L7)
    k_mtail<false><<<dim3(3, 10, 16), 256, 0, stream>>>(
        bufA, bufB, qw + 16128, scales, smaxf, bnp, luts, 4, 5, 14,
        nullptr, nullptr, nullptr);
    k_mtail<false><<<dim3(3, 10, 16), 256, 0, stream>>>(
        bufB, bufA, qw + 25344, scales, smaxf, bnp, luts, 5, 6, 15,
        nullptr, nullptr, nullptr);
    k_mtail<false><<<dim3(3, 10, 16), 256, 0, stream>>>(
        bufA, bufB, qw + 34560, scales, smaxf, bnp, luts, 6, 7, 16,
        nullptr, nullptr, nullptr);
    k_mtail<true><<<dim3(3, 10, 16), 256, 0, stream>>>(
        bufB, bufA, qw + 43776, scales, smaxf, bnp, luts, 7, 8, 17,
        qw + 52992, b9, (float*)d_out);

    (void)in_sizes; (void)n_in; (void)out_size; (void)ws_size;
}

// Round 5
// 197.293 us; speedup vs baseline: 1.0587x; 1.0587x over previous
//
#include <hip/hip_runtime.h>
#include <stdint.h>

#define EPSV 1e-5f

typedef int v4i __attribute__((ext_vector_type(4)));

__device__ __forceinline__ v4i mfma16(v4i a, v4i b, v4i c) {
    return __builtin_amdgcn_mfma_i32_16x16x64_i8(a, b, c, 0, 0, 0);
}

// epilogue first stage: BN + ReLU-u4 quant -> r index in [0,15].
__device__ __forceinline__ int q_r(int s, float fscale, float inv, float beta,
                                   float s_relu)
{
#pragma clang fp contract(off)
    float y = (float)s * fscale;
    y = y * inv;
    y = y + beta;
    float r = rintf(y / s_relu);
    r = fminf(fmaxf(r, 0.f), 15.f);
    return (int)r;
}

// ---------------------------------------------------------------------------
// Pack kernel (computes per-layer weight scale in-block; 4-way unrolled
// independent-accumulator scan — value-exact, max is associative).
//  seg B    : conv weights -> MFMA B-fragment order (52992 dwords)
//  seg HEAD : head weights -> MFMA B-fragment order, NT=3 (768 dwords)
//  seg BN   : inv/beta (8*128 floats) + requant LUTs (144 int8)
// ---------------------------------------------------------------------------
struct PackArgs {
    const float* w[9];
    const float* bn[8];
    const float* sc;
    float* smaxf;
    int* qw;
    float* bnp;
    int8_t* lut;
};

#define NB_B    207
#define NB_HEAD 3
#define NB_BN   3

__global__ __launch_bounds__(256) void k_pack(PackArgs a)
{
#pragma clang fp contract(off)
    __shared__ float red[4];
    const int blk = blockIdx.x;
    if (blk < NB_B + NB_HEAD) {
        const int bcum[10] = {0, 256, 1792, 6912, 16128, 25344, 34560, 43776,
                              52992, 53760};
        const int wnn[9] = {432, 4608, 18432, 36864, 36864, 36864, 36864, 36864, 2304};
        const int u = blk * 256 + threadIdx.x;
        int L = 0;
        while (u >= bcum[L + 1]) ++L;          // uniform per block
        const float* w = a.w[L];
        const int n = wnn[L];

        // in-block layer max|w|: 4 independent accumulators (pipelined loads)
        float m0 = 0.f, m1 = 0.f, m2 = 0.f, m3 = 0.f;
        int i = threadIdx.x;
        for (; i + 768 < n; i += 1024) {
            m0 = fmaxf(m0, fabsf(w[i]));
            m1 = fmaxf(m1, fabsf(w[i + 256]));
            m2 = fmaxf(m2, fabsf(w[i + 512]));
            m3 = fmaxf(m3, fabsf(w[i + 768]));
        }
        for (; i < n; i += 256) m0 = fmaxf(m0, fabsf(w[i]));
        float mm = fmaxf(fmaxf(m0, m1), fmaxf(m2, m3));
#pragma unroll
        for (int off = 32; off > 0; off >>= 1) mm = fmaxf(mm, __shfl_down(mm, off));
        if ((threadIdx.x & 63) == 0) red[threadIdx.x >> 6] = mm;
        __syncthreads();
        const float wmax = fmaxf(fmaxf(red[0], red[1]), fmaxf(red[2], red[3]));
        const float s = wmax / 7.0f;
        if (blk * 256 == bcum[L] && threadIdx.x == 0) a.smaxf[L] = wmax;

        if (L < 8) {
            const int CIGA[8] = {1, 4, 8, 16, 16, 16, 16, 16};
            const int COA[8]  = {16, 32, 64, 64, 64, 64, 64, 64};
            const int NTA[8]  = {1, 2, 4, 4, 4, 4, 4, 4};
            const int CINA[8] = {3, 16, 32, 64, 64, 64, 64, 64};
            const int rem = u - bcum[L];
            const int d = rem & 3;
            const int lane = (rem >> 2) & 63;
            const int gnt = rem >> 8;
            const int NT = NTA[L];
            const int nt = gnt % NT;
            const int g = gnt / NT;
            const int CIG = CIGA[L], CIN = CINA[L], CO = COA[L];
            const int TG = 16 / CIG;
            const int nn = nt * 16 + (lane & 15);
            unsigned dw = 0;
            for (int jb = 0; jb < 4; ++jb) {
                const int k = 16 * (lane >> 4) + 4 * d + jb;
                const int tap = g * TG + k / (4 * CIG);
                const int ci = k % (4 * CIG);
                int qv = 0;
                if (tap < 9 && ci < CIN && nn < CO) {
                    float rr = rintf(w[(nn * CIN + ci) * 9 + tap] / s);
                    rr = fminf(fmaxf(rr, -7.f), 7.f);
                    qv = (int)rr;
                }
                dw |= ((unsigned)(qv & 0xff)) << (8 * jb);
            }
            a.qw[u] = (int)dw;
        } else {
            const int uh = u - 52992;           // 0..767
            const int d = uh & 3;
            const int lane = (uh >> 2) & 63;
            const int nt = uh >> 8;             // 0..2
            const int nn = nt * 16 + (lane & 15);
            unsigned dw = 0;
            for (int jb = 0; jb < 4; ++jb) {
                const int ci = 16 * (lane >> 4) + 4 * d + jb;   // K=64 = cin
                int qv = 0;
                if (nn < 36) {
                    float rr = rintf(w[nn * 64 + ci] / s);
                    rr = fminf(fmaxf(rr, -7.f), 7.f);
                    qv = (int)rr;
                }
                dw |= ((unsigned)(qv & 0xff)) << (8 * jb);
            }
            a.qw[u] = (int)dw;
        }
    } else {
        const int id = (blk - NB_B - NB_HEAD) * 256 + threadIdx.x;
        if (id < 512) {
            const int l = id >> 6, c = id & 63;
            const int C[8] = {16, 32, 64, 64, 64, 64, 64, 64};
            if (c < C[l]) {
                const float* bn = a.bn[l];
                const int Cl = C[l];
                float g = bn[c], b = bn[Cl + c], m = bn[2 * Cl + c], v = bn[3 * Cl + c];
                float inv = g / sqrtf(v + EPSV);
                float mi = m * inv;
                a.bnp[l * 128 + c] = inv;
                a.bnp[l * 128 + 64 + c] = b - mi;
            }
        } else if (id < 656) {
            // requant LUTs. l=0..7: relu-u4 r -> next-layer signed code
            //               l=8   : conv0 input double-quant, idx = r0+8
            const int j = id - 512;
            const int l = j >> 4, r = j & 15;
            float code;
            if (l < 8) {
                const float s_relu = a.sc[10 + l];
                const float s_next = (l < 7) ? a.sc[2 + l] : a.sc[9];
                const float v = (float)r * s_relu;          // bit-exact: r*s_relu
                code = fminf(fmaxf(rintf(v / s_next), -8.f), 7.f);
            } else {
                const float v = (float)(r - 8) * a.sc[0];
                code = fminf(fmaxf(rintf(v / a.sc[1]), -8.f), 7.f);
            }
            a.lut[j] = (int8_t)(int)code;
        }
    }
}

// ---------------------------------------------------------------------------
// L0 fused: fake-quant of fp32 x (NCHW) during tile staging + MFMA conv
// 3->16ch + BN/ReLU-quant(LUT)/pool. out NHWC [16][160][320][16].
// grid (10, 40, 16); tile 10x66 px, CIG=1.
// Staging now float4-vectorized: interior 64 px/row via 16 aligned float4
// loads per (row, ch); 2 halo px scalar. Tile built as zeroed byte array —
// identical dwords to the scalar path (same IEEE divide, same LUT).
// ---------------------------------------------------------------------------
__global__ __launch_bounds__(256) void k_conv0(
    const float* __restrict__ x, int8_t* __restrict__ out,
    const int* __restrict__ bfrag, const float* __restrict__ scales,
    const float* __restrict__ smaxf, const float* __restrict__ bnp,
    const int8_t* __restrict__ luts)
{
#pragma clang fp contract(off)
    __shared__ int tile[660];        // 10 * 66
    __shared__ float bnl[128];
    __shared__ int8_t lc[32];        // [0..15] layer0 epi lut, [16..31] input lut
    int8_t* t8 = (int8_t*)tile;

    const int b = blockIdx.z;
    const int py0 = blockIdx.y * 4;
    const int px0 = blockIdx.x * 32;
    const int ty0 = 2 * py0 - 1;
    const int tx0 = 2 * px0 - 1;
    const float s0 = scales[0];

    if (threadIdx.x < 16) lc[threadIdx.x] = luts[threadIdx.x];
    else if (threadIdx.x < 32) lc[threadIdx.x] = luts[128 + threadIdx.x - 16];
    if (threadIdx.x < 128) bnl[threadIdx.x] = bnp[threadIdx.x];
    for (int i = threadIdx.x; i < 660; i += 256) tile[i] = 0;
    __syncthreads();

    // 480 float4 items (ly 0..9, ci 0..2, vi 0..15) + 60 halo scalars
    for (int i = threadIdx.x; i < 540; i += 256) {
        if (i < 480) {
            const int vi = i & 15;
            const int ci = (i >> 4) % 3;
            const int ly = (i >> 4) / 3;
            const int gy = ty0 + ly;
            if ((unsigned)gy < 320u) {
                const int gx = 2 * px0 + 4 * vi;          // aligned, always in-range
                const float4 xv = *(const float4*)&x[((size_t)(b * 3 + ci) * 320 + gy) * 640 + gx];
                const int base = (ly * 66 + 4 * vi + 1) * 4 + ci;
                float r;
                r = rintf(xv.x / s0); r = fminf(fmaxf(r, -8.f), 7.f);
                t8[base]      = lc[16 + (int)r + 8];
                r = rintf(xv.y / s0); r = fminf(fmaxf(r, -8.f), 7.f);
                t8[base + 4]  = lc[16 + (int)r + 8];
                r = rintf(xv.z / s0); r = fminf(fmaxf(r, -8.f), 7.f);
                t8[base + 8]  = lc[16 + (int)r + 8];
                r = rintf(xv.w / s0); r = fminf(fmaxf(r, -8.f), 7.f);
                t8[base + 12] = lc[16 + (int)r + 8];
            }
        } else {
            const int i2 = i - 480;                       // 0..59
            const int ly = i2 / 6, rest = i2 - 6 * ly;
            const int side = rest / 3, ci = rest - 3 * side;
            const int lx = side ? 65 : 0;
            const int gy = ty0 + ly, gx = tx0 + lx;
            if ((unsigned)gy < 320u && (unsigned)gx < 640u) {
                const float xv = x[((size_t)(b * 3 + ci) * 320 + gy) * 640 + gx];
                float r = rintf(xv / s0);
                r = fminf(fmaxf(r, -8.f), 7.f);
                t8[(ly * 66 + lx) * 4 + ci] = lc[16 + (int)r + 8];
            }
        }
    }

    const int lane = threadIdx.x & 63;
    const int wv = threadIdx.x >> 6;
    const v4i bfv = *(const v4i*)&bfrag[lane * 4];
    __syncthreads();

    const int q = lane >> 4;
    const int m = lane & 15;
    const int px_sub = m >> 2;
    const int op = m & 3;
    const int lyb = 2 * wv + (op >> 1);
    const int lxb0 = 2 * px_sub + (op & 1);

    const float sw = smaxf[0] / 7.0f;
    const float fscale = scales[1] * sw;
    const float s_relu = scales[10];
    const float inv = bnl[m];
    const float beta = bnl[64 + m];
    const int py = py0 + wv;

    for (int xs = 0; xs < 8; ++xs) {
        v4i af;
#pragma unroll
        for (int d = 0; d < 4; ++d) {
            int t = 4 * q + d; t = min(t, 8);
            const int ky = (t * 11) >> 5;
            const int kx = t - 3 * ky;
            af[d] = tile[(lyb + ky) * 66 + 8 * xs + lxb0 + kx];
        }
        v4i acc = mfma16(af, bfv, (v4i){0, 0, 0, 0});
        const int px = px0 + 4 * xs + q;
        const int s = max(max(acc[0], acc[1]), max(acc[2], acc[3]));
        const int ri = q_r(s, fscale, inv, beta, s_relu);
        out[((size_t)((b * 160 + py) * 320 + px)) * 16 + m] = lc[ri];
    }
}

// ---------------------------------------------------------------------------
// MFMA pool-conv block (L1..L3). NHWC int8 in/out. B fragments: registers
// when small (L1), else direct per-MFMA global reads (L2-hot).
// A fragments: preloaded NG-deep register array per strip.
// ---------------------------------------------------------------------------
template <int CIG, int CO, int H, int W, int XL>
__global__ __launch_bounds__(256) void k_mpool(
    const int8_t* __restrict__ in, int8_t* __restrict__ out,
    const int* __restrict__ bfrag, const float* __restrict__ scales,
    const float* __restrict__ smaxf, const float* __restrict__ bnp,
    const int8_t* __restrict__ luts, int layer, int sin_idx, int srelu_idx)
{
#pragma clang fp contract(off)
    constexpr int NT = CO / 16;
    constexpr int TG = 16 / CIG;              // taps per K=64 group
    constexpr int NG = (9 + TG - 1) / TG;     // K groups
    constexpr int TLH = 2 * 4 + 2;            // NROWS=4, stride 2
    constexpr int TLW = 2 * 4 * XL + 2;
    constexpr int TILE_DW = TLH * TLW * CIG;
    constexpr bool PRELOAD = (NG * NT <= 8);
    constexpr int Ho = H / 2, Wo = W / 2;

    __shared__ int tile[TILE_DW];
    __shared__ float bnl[128];
    __shared__ int8_t lsh[16];

    const int b = blockIdx.z;
    const int py0 = blockIdx.y * 4;
    const int px0 = blockIdx.x * (4 * XL);
    const int ty0 = 2 * py0 - 1;
    const int tx0 = 2 * px0 - 1;
    const int* gin = (const int*)in;

    // b128 staging: each 4-dword chunk lies within one pixel (CIG >= 4)
    for (int i = threadIdx.x; i < TILE_DW / 4; i += 256) {
        const int j = 4 * i;
        const int cig = j & (CIG - 1);
        const int rest = j / CIG;
        const int lx = rest % TLW;
        const int ly = rest / TLW;
        const int gy = ty0 + ly, gx = tx0 + lx;
        v4i v = {0, 0, 0, 0};
        if ((unsigned)gy < (unsigned)H && (unsigned)gx < (unsigned)W)
            v = *(const v4i*)&gin[((b * H + gy) * W + gx) * CIG + cig];
        *(v4i*)&tile[j] = v;
    }
    if (threadIdx.x < 128) bnl[threadIdx.x] = bnp[layer * 128 + threadIdx.x];
    if (threadIdx.x >= 128 && threadIdx.x < 144)
        lsh[threadIdx.x - 128] = luts[layer * 16 + threadIdx.x - 128];

    const int lane = threadIdx.x & 63;
    const int wv = threadIdx.x >> 6;
    v4i breg[PRELOAD ? NG * NT : 1];
    if constexpr (PRELOAD) {
#pragma unroll
        for (int i = 0; i < NG * NT; ++i)
            breg[i] = *(const v4i*)&bfrag[(i * 64 + lane) * 4];
    }
    __syncthreads();

    const int q = lane >> 4;
    const int m = lane & 15;

    const float fscale = scales[sin_idx] * (smaxf[layer] / 7.0f);
    const float s_relu = scales[srelu_idx];

    const int px_sub = m >> 2;
    const int op = m & 3;
    const int lyb = 2 * wv + (op >> 1);
    const int lxb0 = 2 * px_sub + (op & 1);
    const int py = py0 + wv;

    for (int xs = 0; xs < XL; ++xs) {
        // --- preload all NG A-fragments (independent, pipelined) ---
        v4i afv[NG];
#pragma unroll
        for (int g = 0; g < NG; ++g) {
            if constexpr (CIG == 16) {
                const int ky = (g * 11) >> 5;
                const int kx = g - 3 * ky;
                const int addr = ((lyb + ky) * TLW + (8 * xs + lxb0 + kx)) * 16 + 4 * q;
                afv[g] = *(const v4i*)&tile[addr];
            } else if constexpr (CIG == 8) {
                int t = 2 * g + (q >> 1); t = min(t, 8);
                const int ky = (t * 11) >> 5;
                const int kx = t - 3 * ky;
                const int addr = ((lyb + ky) * TLW + (8 * xs + lxb0 + kx)) * 8 + 4 * (q & 1);
                afv[g] = *(const v4i*)&tile[addr];
            } else {  // CIG == 4
                int t = 4 * g + q; t = min(t, 8);
                const int ky = (t * 11) >> 5;
                const int kx = t - 3 * ky;
                const int addr = ((lyb + ky) * TLW + (8 * xs + lxb0 + kx)) * 4;
                afv[g] = *(const v4i*)&tile[addr];
            }
        }

        v4i acc[NT];
#pragma unroll
        for (int j = 0; j < NT; ++j) acc[j] = (v4i){0, 0, 0, 0};

#pragma unroll
        for (int g = 0; g < NG; ++g) {
#pragma unroll
            for (int j = 0; j < NT; ++j) {
                v4i bf;
                if constexpr (PRELOAD) bf = breg[g * NT + j];
                else bf = *(const v4i*)&bfrag[((g * NT + j) * 64 + lane) * 4];
                acc[j] = mfma16(afv[g], bf, acc[j]);
            }
        }

        const int px = px0 + 4 * xs + q;
        int8_t* po = out + ((size_t)((b * Ho + py) * Wo + px)) * CO + m;
#pragma unroll
        for (int j = 0; j < NT; ++j) {
            const int co = j * 16 + m;
            const int s = max(max(acc[j][0], acc[j][1]), max(acc[j][2], acc[j][3]));
            const int ri = q_r(s, fscale, bnl[co], bnl[64 + co], s_relu);
            po[j * 16] = lsh[ri];
        }
    }
}

// ---------------------------------------------------------------------------
// Tail conv (L4..L7): 20x40x64, 3x3 SAME, nonpool. grid (3,10,16), 4 waves,
// 2 rows x 16 px per block. B preloaded to regs before the barrier; A
// preloaded 9-deep; pure-register MFMA burst. FUSED: 1x1 head + bias.
// ---------------------------------------------------------------------------
template <bool FUSED>
__global__ __launch_bounds__(256) void k_mtail(
    const int8_t* __restrict__ in, int8_t* __restrict__ out,
    const int* __restrict__ bfrag, const float* __restrict__ scales,
    const float* __restrict__ smaxf, const float* __restrict__ bnp,
    const int8_t* __restrict__ luts, int layer, int sin_idx, int srelu_idx,
    const int* __restrict__ hfrag, const float* __restrict__ b9,
    float* __restrict__ dout)
{
#pragma clang fp contract(off)
    constexpr int TLW = 18;
    constexpr int TILE_DW = 4 * TLW * 16;
    __shared__ int tile[TILE_DW];
    __shared__ float bnl[128];
    __shared__ int8_t lsh[16];
    __shared__ int code_dw[FUSED ? 512 : 1];

    const int b = blockIdx.z;
    const int py0 = blockIdx.y * 2;
    const int px0 = blockIdx.x * 16;
    const int ty0 = py0 - 1;
    const int tx0 = px0 - 1;
    const int* gin = (const int*)in;

    for (int i = threadIdx.x; i < TILE_DW / 4; i += 256) {
        const int j = 4 * i;
        const int cig = j & 15;
        const int rest = j >> 4;
        const int lx = rest % TLW;
        const int ly = rest / TLW;
        const int gy = ty0 + ly, gx = tx0 + lx;
        v4i v = {0, 0, 0, 0};
        if ((unsigned)gy < 20u && (unsigned)gx < 40u)
            v = *(const v4i*)&gin[((b * 20 + gy) * 40 + gx) * 16 + cig];
        *(v4i*)&tile[j] = v;
    }
    if (threadIdx.x < 128) bnl[threadIdx.x] = bnp[layer * 128 + threadIdx.x];
    if (threadIdx.x >= 128 && threadIdx.x < 144)
        lsh[threadIdx.x - 128] = luts[layer * 16 + threadIdx.x - 128];

    const int lane = threadIdx.x & 63;
    const int wv = threadIdx.x >> 6;
    const int q = lane >> 4;
    const int m = lane & 15;
    const int wrow = wv >> 1;
    const int nt0 = (wv & 1) * 2;

    // B preload BEFORE barrier: latency overlaps the staging drain
    v4i bl[18];
#pragma unroll
    for (int g = 0; g < 9; ++g)
#pragma unroll
        for (int jj = 0; jj < 2; ++jj)
            bl[g * 2 + jj] = *(const v4i*)&bfrag[((g * 4 + nt0 + jj) * 64 + lane) * 4];
    __syncthreads();

    const float fscale = scales[sin_idx] * (smaxf[layer] / 7.0f);
    const float s_relu = scales[srelu_idx];

    // A preload: 9 independent b128 reads, then pure-register MFMA burst
    v4i afv[9];
#pragma unroll
    for (int g = 0; g < 9; ++g) {
        const int ky = (g * 11) >> 5;
        const int kx = g - 3 * ky;
        afv[g] = *(const v4i*)&tile[((wrow + ky) * TLW + (m + kx)) * 16 + 4 * q];
    }

    v4i acc[2];
    acc[0] = (v4i){0, 0, 0, 0};
    acc[1] = (v4i){0, 0, 0, 0};
#pragma unroll
    for (int g = 0; g < 9; ++g)
#pragma unroll
        for (int jj = 0; jj < 2; ++jj)
            acc[jj] = mfma16(afv[g], bl[g * 2 + jj], acc[jj]);

    const int py = py0 + wrow;
#pragma unroll
    for (int jj = 0; jj < 2; ++jj) {
        const int co = (nt0 + jj) * 16 + m;
        const float inv = bnl[co], beta = bnl[64 + co];
#pragma unroll
        for (int r = 0; r < 4; ++r) {
            const int px = px0 + 4 * q + r;
            const int ri = q_r(acc[jj][r], fscale, inv, beta, s_relu);
            if constexpr (FUSED) {
                ((int8_t*)code_dw)[(wrow * 16 + 4 * q + r) * 64 + co] = lsh[ri];
            } else {
                if (px < 40)
                    out[((size_t)((b * 20 + py) * 40 + px)) * 64 + co] = lsh[ri];
            }
        }
    }

    if constexpr (FUSED) {
        __syncthreads();
        if (wv < 2) {
            const v4i ha = *(const v4i*)&code_dw[(wv * 16 + m) * 16 + 4 * q];
            const float fs = scales[9] * (smaxf[8] / 7.0f);
            const int py2 = py0 + wv;
#pragma unroll
            for (int nt = 0; nt < 3; ++nt) {
                const v4i hb = *(const v4i*)&hfrag[(nt * 64 + lane) * 4];
                const v4i hacc = mfma16(ha, hb, (v4i){0, 0, 0, 0});
                const int co = nt * 16 + m;
                if (co < 36) {
                    const float bias = b9[co];
#pragma unroll
                    for (int r = 0; r < 4; ++r) {
                        const int px = px0 + 4 * q + r;
                        if (px < 40) {
                            float yv = (float)hacc[r] * fs;
                            dout[((size_t)(b * 36 + co)) * 800 + py2 * 40 + px] = yv + bias;
                        }
                    }
                }
            }
        }
    }
}

// ---------------------------------------------------------------------------
// Launch: 9 regular dispatches
// ---------------------------------------------------------------------------
extern "C" void kernel_launch(void* const* d_in, const int* in_sizes, int n_in,
                              void* d_out, int out_size, void* d_ws, size_t ws_size,
                              hipStream_t stream)
{
    const float* x = (const float*)d_in[0];
    const float* w[9];
    for (int i = 0; i < 9; i++) w[i] = (const float*)d_in[1 + i];
    const float* b9 = (const float*)d_in[10];
    const float* bn[8];
    for (int i = 0; i < 8; i++) bn[i] = (const float*)d_in[11 + i];
    const float* scales = (const float*)d_in[19];

    int8_t* base = (int8_t*)d_ws;
    int8_t* bufA = base;                             // 13,107,200 B
    int8_t* bufB = base + 13107200;                  // 13,107,200 B
    int*     qw  = (int*)(base + 26214400);          // 53760 dwords
    float* smaxf = (float*)(base + 26429440);        // 9 floats
    float*   bnp = (float*)(base + 26429504);        // 1024 floats
    int8_t* luts = base + 26433600;                  // 144 B

    PackArgs pa;
    for (int i = 0; i < 9; i++) pa.w[i] = w[i];
    for (int i = 0; i < 8; i++) pa.bn[i] = bn[i];
    pa.sc = scales; pa.smaxf = smaxf;
    pa.qw = qw; pa.bnp = bnp; pa.lut = luts;
    k_pack<<<NB_B + NB_HEAD + NB_BN, 256, 0, stream>>>(pa);

    // L0: fp32 x -> NHWC codes [16][160][320][16] in bufB
    k_conv0<<<dim3(10, 40, 16), 256, 0, stream>>>(
        x, bufB, qw, scales, smaxf, bnp, luts);

    // L1: CIG=4, CO=32, 160x320 -> 80x160, XL=8 (32 px/block)
    k_mpool<4, 32, 160, 320, 8><<<dim3(5, 20, 16), 256, 0, stream>>>(
        bufB, bufA, qw + 256, scales, smaxf, bnp, luts, 1, 2, 11);
    // L2: CIG=8, CO=64, 80x160 -> 40x80 (direct global B)
    k_mpool<8, 64, 80, 160, 2><<<dim3(10, 10, 16), 256, 0, stream>>>(
        bufA, bufB, qw + 1792, scales, smaxf, bnp, luts, 2, 3, 12);
    // L3: CIG=16, CO=64, 40x80 -> 20x40 (direct global B)
    k_mpool<16, 64, 40, 80, 1><<<dim3(10, 5, 16), 256, 0, stream>>>(
        bufB, bufA, qw + 6912, scales, smaxf, bnp, luts, 3, 4, 13);

    // L4..L7 (+ fused head on L7)
    k_mtail<false><<<dim3(3, 10, 16), 256, 0, stream>>>(
        bufA, bufB, qw + 16128, scales, smaxf, bnp, luts, 4, 5, 14,
        nullptr, nullptr, nullptr);
    k_mtail<false><<<dim3(3, 10, 16), 256, 0, stream>>>(
        bufB, bufA, qw + 25344, scales, smaxf, bnp, luts, 5, 6, 15,
        nullptr, nullptr, nullptr);
    k_mtail<false><<<dim3(3, 10, 16), 256, 0, stream>>>(
        bufA, bufB, qw + 34560, scales, smaxf, bnp, luts, 6, 7, 16,
        nullptr, nullptr, nullptr);
    k_mtail<true><<<dim3(3, 10, 16), 256, 0, stream>>>(
        bufB, bufA, qw + 43776, scales, smaxf, bnp, luts, 7, 8, 17,
        qw + 52992, b9, (float*)d_out);

    (void)in_sizes; (void)n_in; (void)out_size; (void)ws_size;
}